// Round 7
// baseline (284.798 us; speedup 1.0000x reference)
//
#include <hip/hip_runtime.h>
#include <cstdint>
#include <cstddef>

// B=16, N=1024, D=768, H=12, HS=64, L=2
// R7 changes vs R6 (theory: HBM-side staging still latency-underdepth):
//  - gemm1/gemmf: asymmetric pipeline. A (HBM-streamed) depth-3 via 4 bufs;
//    B (L2-resident weights) depth-1 via 2 bufs. Issue order B-then-A so
//    WAITB(2) waits exactly stage(it) with A(it+2) left in flight.
//    LDS 48KB -> still 3 blocks/CU.
//  - circ: B (Vt, HBM-streamed) depth-4 via 5 bufs (WAITB(6)); alpha LDS
//    shrunk 8->4 copies (A-frags = two ds b64 reads, 8B-aligned).
//    LDS 50.3KB -> still 3 blocks/CU.
//
// ws layout (bytes):
//  [0, 25165824)          slotA : xn_bf16 -> z1_bf16
//  [25165824, 50331648)   Vt    : gemm1 out ; reused as gbf after circ
//  [50331648, 75497472)   slotX : x2_bf16 (circ out, read by gemmf1 + final)
//  [75497472, 76677120)   W2t
//  [76677120, 79036416)   Wft

typedef __attribute__((ext_vector_type(8))) short bf16x8;
typedef __attribute__((ext_vector_type(4))) short bf16x4;
typedef __attribute__((ext_vector_type(4))) float f32x4;
typedef __attribute__((ext_vector_type(4))) unsigned short us4;

__device__ __forceinline__ unsigned short f2bf(float f) {
  unsigned int u = __builtin_bit_cast(unsigned int, f);
  u += 0x7FFFu + ((u >> 16) & 1u);
  return (unsigned short)(u >> 16);
}
__device__ __forceinline__ float bf2f(unsigned short u) {
  return __builtin_bit_cast(float, (unsigned int)u << 16);
}

__device__ __forceinline__ void g2l16(const void* g, void* l) {
  __builtin_amdgcn_global_load_lds(
      (const __attribute__((address_space(1))) unsigned int*)g,
      (__attribute__((address_space(3))) unsigned int*)l,
      16, 0, 0);
}

#define WAITB(n) asm volatile("s_waitcnt vmcnt(" #n ") lgkmcnt(0)\n\ts_barrier" ::: "memory")

// ---------------- pack kernels ----------------
__global__ __launch_bounds__(256) void pack_w2t(const float* __restrict__ Wv,
                                                unsigned short* __restrict__ W2t) {
  int o = blockIdx.x * 256 + threadIdx.x;
  int np = o / 768, d = o - np * 768;
  int h = np >> 6, k = np & 63;
  W2t[o] = f2bf(Wv[h * 49152 + d * 64 + k]);
}

__global__ __launch_bounds__(256) void pack_wft(const float* __restrict__ Wf,
                                                unsigned short* __restrict__ Wft) {
  int o = blockIdx.x * 256 + threadIdx.x;
  int l = o / 589824, rem = o - l * 589824;
  int np = rem / 768, d = rem - np * 768;
  Wft[o] = f2bf(Wf[l * 589824 + d * 768 + np]);
}

// ---------------- row kernels ----------------
__device__ __forceinline__ void wave_reduce2(float& s, float& s2) {
#pragma unroll
  for (int off = 32; off > 0; off >>= 1) {
    s += __shfl_down(s, off);
    s2 += __shfl_down(s2, off);
  }
  s = __shfl(s, 0);
  s2 = __shfl(s2, 0);
}

__global__ __launch_bounds__(256) void ln1_kernel(const float* __restrict__ x,
                                                  const float* __restrict__ sc,
                                                  const float* __restrict__ bi,
                                                  unsigned short* __restrict__ out) {
  int row = blockIdx.x * 4 + (threadIdx.x >> 6);
  int lane = threadIdx.x & 63;
  size_t base = (size_t)row * 768;
  float4 v[3];
#pragma unroll
  for (int j = 0; j < 3; ++j) v[j] = *(const float4*)(x + base + lane * 4 + j * 256);
  float s = 0.f, s2 = 0.f;
#pragma unroll
  for (int j = 0; j < 3; ++j) {
    s += v[j].x + v[j].y + v[j].z + v[j].w;
    s2 += v[j].x * v[j].x + v[j].y * v[j].y + v[j].z * v[j].z + v[j].w * v[j].w;
  }
  wave_reduce2(s, s2);
  float mu = s * (1.0f / 768.0f);
  float var = s2 * (1.0f / 768.0f) - mu * mu;
  float r = rsqrtf(var + 1e-6f);
#pragma unroll
  for (int j = 0; j < 3; ++j) {
    int d = lane * 4 + j * 256;
    float4 scv = *(const float4*)(sc + d);
    float4 biv = *(const float4*)(bi + d);
    us4 o;
    o[0] = f2bf((v[j].x - mu) * r * scv.x + biv.x);
    o[1] = f2bf((v[j].y - mu) * r * scv.y + biv.y);
    o[2] = f2bf((v[j].z - mu) * r * scv.z + biv.z);
    o[3] = f2bf((v[j].w - mu) * r * scv.w + biv.w);
    *(us4*)(out + base + d) = o;
  }
}

__global__ __launch_bounds__(256) void lnswish_kernel(const unsigned short* __restrict__ g,
                                                      const float* __restrict__ sc,
                                                      const float* __restrict__ bi,
                                                      unsigned short* __restrict__ out) {
  int row = blockIdx.x * 4 + (threadIdx.x >> 6);
  int lane = threadIdx.x & 63;
  size_t base = (size_t)row * 768;
  float v[3][4];
#pragma unroll
  for (int j = 0; j < 3; ++j) {
    us4 gv = *(const us4*)(g + base + lane * 4 + j * 256);
#pragma unroll
    for (int q = 0; q < 4; ++q) v[j][q] = bf2f(gv[q]);
  }
  float s = 0.f, s2 = 0.f;
#pragma unroll
  for (int j = 0; j < 3; ++j)
#pragma unroll
    for (int q = 0; q < 4; ++q) { s += v[j][q]; s2 += v[j][q] * v[j][q]; }
  wave_reduce2(s, s2);
  float mu = s * (1.0f / 768.0f);
  float var = s2 * (1.0f / 768.0f) - mu * mu;
  float r = rsqrtf(var + 1e-6f);
#pragma unroll
  for (int j = 0; j < 3; ++j) {
    int d = lane * 4 + j * 256;
    float4 scv = *(const float4*)(sc + d);
    float4 biv = *(const float4*)(bi + d);
    const float* scp = &scv.x;
    const float* bip = &biv.x;
    us4 o;
#pragma unroll
    for (int q = 0; q < 4; ++q) {
      float z = (v[j][q] - mu) * r * scp[q] + bip[q];
      o[q] = f2bf(z / (1.0f + __expf(-z)));
    }
    *(us4*)(out + base + d) = o;
  }
}

__global__ __launch_bounds__(256) void final_kernel(const unsigned short* __restrict__ g,
                                                    const float* __restrict__ sc,
                                                    const float* __restrict__ bi,
                                                    const unsigned short* __restrict__ x2,
                                                    float* __restrict__ out) {
  int row = blockIdx.x * 4 + (threadIdx.x >> 6);
  int lane = threadIdx.x & 63;
  size_t base = (size_t)row * 768;
  float v[3][4];
#pragma unroll
  for (int j = 0; j < 3; ++j) {
    us4 gv = *(const us4*)(g + base + lane * 4 + j * 256);
#pragma unroll
    for (int q = 0; q < 4; ++q) v[j][q] = bf2f(gv[q]);
  }
  float s = 0.f, s2 = 0.f;
#pragma unroll
  for (int j = 0; j < 3; ++j)
#pragma unroll
    for (int q = 0; q < 4; ++q) { s += v[j][q]; s2 += v[j][q] * v[j][q]; }
  wave_reduce2(s, s2);
  float mu = s * (1.0f / 768.0f);
  float var = s2 * (1.0f / 768.0f) - mu * mu;
  float r = rsqrtf(var + 1e-6f);
#pragma unroll
  for (int j = 0; j < 3; ++j) {
    int d = lane * 4 + j * 256;
    float4 scv = *(const float4*)(sc + d);
    float4 biv = *(const float4*)(bi + d);
    us4 xv = *(const us4*)(x2 + base + d);
    const float* scp = &scv.x;
    const float* bip = &biv.x;
    float4 o;
    float* op = &o.x;
#pragma unroll
    for (int q = 0; q < 4; ++q) {
      float z = (v[j][q] - mu) * r * scp[q] + bip[q];
      float sw = z / (1.0f + __expf(-z));
      float t = sw + bf2f(xv[q]);
      float ax = fabsf(t);
      op[q] = ax + __logf(1.0f + __expf(-2.0f * ax)) - 0.69314718055994531f;
    }
    *(float4*)(out + base + d) = o;
  }
}

// ---- asymmetric GEMM core: 128x128, BK=32; A depth-3 (4 buf), B depth-1 (2 buf)
__device__ __forceinline__ void gemm_core(const unsigned short* __restrict__ A,
                                          const unsigned short* __restrict__ Bt,
                                          int K, int m0, int n0,
                                          unsigned short* sA, unsigned short* sB,
                                          f32x4 acc[4][4]) {
  const int tid = threadIdx.x;
  const int wave = tid >> 6, lane = tid & 63;
  const int wm = (wave >> 1) << 6, wn = (wave & 1) << 6;
  const int fm = lane & 15, fq = lane >> 4;
  const int r0 = tid >> 2, r1 = r0 + 64;
  const int cg = tid & 3;
  const int cs0 = (cg ^ ((r0 >> 1) & 3)) << 3;
  const int cs1 = (cg ^ ((r1 >> 1) & 3)) << 3;
  const int ld0 = r0 * 32 + (cg << 3);
  const int ld1 = r1 * 32 + (cg << 3);
  const int niter = K >> 5;

#define STAGEA(k0v, buf)                                                      \
  {                                                                           \
    unsigned short* dA = sA + (buf) * 4096;                                   \
    g2l16(A + (size_t)(m0 + r0) * K + (k0v) + cs0, dA + ld0);                 \
    g2l16(A + (size_t)(m0 + r1) * K + (k0v) + cs1, dA + ld1);                 \
  }
#define STAGEBW(k0v, buf)                                                     \
  {                                                                           \
    unsigned short* dB = sB + (buf) * 4096;                                   \
    g2l16(Bt + (size_t)(n0 + r0) * K + (k0v) + cs0, dB + ld0);                \
    g2l16(Bt + (size_t)(n0 + r1) * K + (k0v) + cs1, dB + ld1);                \
  }
#define GCOMP(it)                                                             \
  {                                                                           \
    const unsigned short* pA = sA + ((it) & 3) * 4096;                        \
    const unsigned short* pB = sB + ((it) & 1) * 4096;                        \
    bf16x8 aq[4], bq[4];                                                      \
    _Pragma("unroll") for (int t = 0; t < 4; ++t) {                           \
      int ra = wm + (t << 4) + fm;                                            \
      int rb = wn + (t << 4) + fm;                                            \
      aq[t] = *(const bf16x8*)(pA + (ra << 5) + ((fq ^ ((ra >> 1) & 3)) << 3)); \
      bq[t] = *(const bf16x8*)(pB + (rb << 5) + ((fq ^ ((rb >> 1) & 3)) << 3)); \
    }                                                                         \
    _Pragma("unroll") for (int mt = 0; mt < 4; ++mt)                          \
    _Pragma("unroll") for (int nt = 0; nt < 4; ++nt)                          \
      acc[mt][nt] = __builtin_amdgcn_mfma_f32_16x16x32_bf16(aq[mt], bq[nt],   \
                                                            acc[mt][nt], 0, 0, 0); \
  }

  // Prologue FIFO: A0, A1, B0, A2  -> at it=0, WAITB(2) leaves A2 in flight.
  STAGEA(0, 0);
  STAGEA(32, 1);
  STAGEBW(0, 0);
  STAGEA(64, 2);
  for (int it = 0; it < niter; ++it) {
    if (it < niter - 2) { WAITB(2); } else { WAITB(0); }
    if (it + 1 < niter) STAGEBW((it + 1) << 5, (it + 1) & 1);
    if (it + 3 < niter) STAGEA((it + 3) << 5, (it + 3) & 3);
    GCOMP(it);
  }
#undef STAGEA
#undef STAGEBW
}

__device__ __forceinline__ void decode_mn_768(int f, int& m0, int& n0) {
  int xcd = f & 7, s = f >> 3;
  int g = s / 6, bx = s - g * 6;
  m0 = (xcd + g * 8) << 7;
  n0 = bx << 7;
}

// GEMM1: xn @ W2t -> Vt[h][b*64+k][n] (bf16)
__global__ __launch_bounds__(256, 3) void gemm1_kernel(const unsigned short* __restrict__ A,
                                                       const unsigned short* __restrict__ Bt,
                                                       unsigned short* __restrict__ Vt) {
  __shared__ unsigned short sA[4 * 4096];
  __shared__ unsigned short sB[2 * 4096];
  f32x4 acc[4][4] = {};
  int m0, n0;
  decode_mn_768(blockIdx.x, m0, n0);
  gemm_core(A, Bt, 768, m0, n0, sA, sB, acc);
  const int wave = threadIdx.x >> 6, lane = threadIdx.x & 63;
  const int wm = (wave >> 1) << 6, wn = (wave & 1) << 6;
  const int fm = lane & 15, fq = lane >> 4;
#pragma unroll
  for (int mt = 0; mt < 4; ++mt) {
    int rowb = m0 + wm + (mt << 4) + (fq << 2);
    int b = rowb >> 10, n = rowb & 1023;
#pragma unroll
    for (int nt = 0; nt < 4; ++nt) {
      int col = n0 + wn + (nt << 4) + fm;
      int h = col >> 6, ck = col & 63;
      size_t off = ((size_t)h << 20) + (size_t)((b << 6) + ck) * 1024 + n;
      us4 v;
#pragma unroll
      for (int r = 0; r < 4; ++r) v[r] = f2bf(acc[mt][nt][r]);
      *(us4*)(Vt + off) = v;
    }
  }
}

// circGEMM: A from alpha (4 shifted LDS copies, b64-pair reads), B = Vt_h
// 5-buffer depth-4 B pipeline. Epilogue: x2 = x + y (bf16).
__global__ __launch_bounds__(256, 3) void circ_kernel(const float* __restrict__ alpha,
                                                      const unsigned short* __restrict__ Vt,
                                                      const float* __restrict__ xin,
                                                      unsigned short* __restrict__ x2bf) {
  __shared__ unsigned short sAc[4 * 1168];
  __shared__ unsigned short sB[5 * 4096];
  f32x4 acc[4][4] = {};
  int f = blockIdx.x;
  int xcd = f & 7, s = f >> 3;
  int h = s >> 3, t = s & 7;
  int mr = xcd >> 1, nr = xcd & 1;
  int m0 = ((mr << 1) + (t >> 2)) << 7;
  int n0 = ((nr << 2) + (t & 3)) << 7;

  const int tid = threadIdx.x;
  const int wave = tid >> 6, lane = tid & 63;
  const int wm = (wave >> 1) << 6, wn = (wave & 1) << 6;
  const int fm = lane & 15, fq = lane >> 4;

  // copies: sAc[c][u] holds value for t-index d = u + c (c = d & 3)
  const float* ah = alpha + (h << 10);
#pragma unroll
  for (int c = 0; c < 4; ++c)
    for (int u = tid; u < 1160; u += 256)
      sAc[c * 1168 + u] = f2bf(ah[(m0 - 897 - u - c) & 1023]);
  asm volatile("s_waitcnt vmcnt(0)" ::: "memory");  // drain fill loads from FIFO

  const unsigned short* Bt = Vt + ((size_t)h << 20);
  const int r0 = tid >> 2, r1 = r0 + 64;
  const int cg = tid & 3;
  const int cs0 = (cg ^ ((r0 >> 1) & 3)) << 3;
  const int cs1 = (cg ^ ((r1 >> 1) & 3)) << 3;
  const int ld0 = r0 * 32 + (cg << 3);
  const int ld1 = r1 * 32 + (cg << 3);

#define STAGEB(k0v, buf)                                                      \
  {                                                                           \
    unsigned short* dB = sB + (buf) * 4096;                                   \
    g2l16(Bt + (size_t)(n0 + r0) * 1024 + (k0v) + cs0, dB + ld0);             \
    g2l16(Bt + (size_t)(n0 + r1) * 1024 + (k0v) + cs1, dB + ld1);             \
  }
#define CCOMP(it, bsl)                                                        \
  {                                                                           \
    const unsigned short* pB = sB + (bsl) * 4096;                             \
    int k0v = (it) << 5;                                                      \
    bf16x8 aq[4], bq[4];                                                      \
    _Pragma("unroll") for (int t_ = 0; t_ < 4; ++t_) {                        \
      int rl = wm + (t_ << 4) + fm;                                           \
      int d = k0v + (fq << 3) + 127 - rl;                                     \
      int c2 = d & 3;                                                         \
      const unsigned short* ap = sAc + c2 * 1168 + (d - c2);                  \
      bf16x4 lo = *(const bf16x4*)ap;                                         \
      bf16x4 hi = *(const bf16x4*)(ap + 4);                                   \
      aq[t_] = __builtin_shufflevector(lo, hi, 0, 1, 2, 3, 4, 5, 6, 7);       \
      int rb = wn + (t_ << 4) + fm;                                           \
      bq[t_] = *(const bf16x8*)(pB + (rb << 5) + ((fq ^ ((rb >> 1) & 3)) << 3)); \
    }                                                                         \
    _Pragma("unroll") for (int mt = 0; mt < 4; ++mt)                          \
    _Pragma("unroll") for (int nt = 0; nt < 4; ++nt)                          \
      acc[mt][nt] = __builtin_amdgcn_mfma_f32_16x16x32_bf16(aq[mt], bq[nt],   \
                                                            acc[mt][nt], 0, 0, 0); \
  }

  STAGEB(0, 0);
  STAGEB(32, 1);
  STAGEB(64, 2);
  STAGEB(96, 3);
  int bs = 4, bc = 0;
  for (int it = 0; it < 32; ++it) {
    if (it <= 28) { WAITB(6); }
    else if (it == 29) { WAITB(4); }
    else if (it == 30) { WAITB(2); }
    else { WAITB(0); }
    if (it + 4 < 32) {
      STAGEB((it + 4) << 5, bs);
      bs = (bs == 4) ? 0 : bs + 1;
    }
    CCOMP(it, bc);
    bc = (bc == 4) ? 0 : bc + 1;
  }
#undef STAGEB

  // epilogue: x2 = x + y (bf16)
#pragma unroll
  for (int mt = 0; mt < 4; ++mt) {
    int ib = m0 + wm + (mt << 4) + (fq << 2);
#pragma unroll
    for (int nt = 0; nt < 4; ++nt) {
      int c = n0 + wn + (nt << 4) + fm;
      int b = c >> 6, k = c & 63;
      size_t off = ((size_t)(b << 10) + ib) * 768 + (h << 6) + k;
#pragma unroll
      for (int r = 0; r < 4; ++r) {
        float val = acc[mt][nt][r] + xin[off + (size_t)r * 768];
        x2bf[off + (size_t)r * 768] = f2bf(val);
      }
    }
  }
}

// FFN GEMM: A(bf16) @ Wt + bias -> g (bf16)
__global__ __launch_bounds__(256, 3) void gemmf_kernel(const unsigned short* __restrict__ A,
                                                       const unsigned short* __restrict__ Bt,
                                                       const float* __restrict__ bias,
                                                       unsigned short* __restrict__ g) {
  __shared__ unsigned short sA[4 * 4096];
  __shared__ unsigned short sB[2 * 4096];
  f32x4 acc[4][4] = {};
  int m0, n0;
  decode_mn_768(blockIdx.x, m0, n0);
  gemm_core(A, Bt, 768, m0, n0, sA, sB, acc);
  const int wave = threadIdx.x >> 6, lane = threadIdx.x & 63;
  const int wm = (wave >> 1) << 6, wn = (wave & 1) << 6;
  const int fm = lane & 15, fq = lane >> 4;
#pragma unroll
  for (int mt = 0; mt < 4; ++mt) {
    int rowb = m0 + wm + (mt << 4) + (fq << 2);
#pragma unroll
    for (int nt = 0; nt < 4; ++nt) {
      int col = n0 + wn + (nt << 4) + fm;
      float bc = bias[col];
#pragma unroll
      for (int r = 0; r < 4; ++r)
        g[(size_t)(rowb + r) * 768 + col] = f2bf(acc[mt][nt][r] + bc);
    }
  }
}

extern "C" void kernel_launch(void* const* d_in, const int* in_sizes, int n_in,
                              void* d_out, int out_size, void* d_ws, size_t ws_size,
                              hipStream_t stream) {
  const float* x = (const float*)d_in[0];
  const float* ln1_s = (const float*)d_in[1];
  const float* ln1_b = (const float*)d_in[2];
  const float* Wv = (const float*)d_in[3];
  const float* alpha = (const float*)d_in[4];
  const float* Wf = (const float*)d_in[5];
  const float* bf = (const float*)d_in[6];
  const float* lnf_s = (const float*)d_in[7];
  const float* lnf_b = (const float*)d_in[8];
  float* out = (float*)d_out;

  char* ws = (char*)d_ws;
  unsigned short* slotA = (unsigned short*)ws;
  unsigned short* Vt = (unsigned short*)(ws + 25165824);
  unsigned short* gbf = Vt;
  unsigned short* slotX = (unsigned short*)(ws + 50331648);
  unsigned short* W2t = (unsigned short*)(ws + 75497472);
  unsigned short* Wft = (unsigned short*)(ws + 76677120);

  pack_w2t<<<2304, 256, 0, stream>>>(Wv, W2t);
  pack_wft<<<4608, 256, 0, stream>>>(Wf, Wft);

  ln1_kernel<<<4096, 256, 0, stream>>>(x, ln1_s, ln1_b, slotA);
  gemm1_kernel<<<768, 256, 0, stream>>>(slotA, W2t, Vt);
  circ_kernel<<<768, 256, 0, stream>>>(alpha, Vt, x, slotX);
  gemmf_kernel<<<768, 256, 0, stream>>>(slotX, Wft, bf, gbf);
  lnswish_kernel<<<4096, 256, 0, stream>>>(gbf, lnf_s, lnf_b, slotA);
  gemmf_kernel<<<768, 256, 0, stream>>>(slotA, Wft + 589824, bf + 768, gbf);
  final_kernel<<<4096, 256, 0, stream>>>(gbf, lnf_s + 768, lnf_b + 768, slotX, out);
}